// Round 2
// baseline (1401.405 us; speedup 1.0000x reference)
//
#include <hip/hip_runtime.h>
#include <stdint.h>

// Reference: per image b, per nonzero id in weak_mask, count distinct float32
// prediction values. Lb = distinct_total(b) - nb(b); loss = fold over b of
// loss = (loss + Lb) / nb  (when nb > 0). tgt_img / mask are unused.
//
// Implementation: global hash set over keys (b, id, float-bits) with 64-bit
// slots + atomicCAS linear probing. Exact distinct counting (float32
// duplicate collisions are ~500/image and affect the result).
// Table capped at 2^24 slots (134 MB) so it stays Infinity-Cache-resident;
// the 16 batches are processed in passes sized for <=60% load factor.

static constexpr int      kBatches    = 16;
static constexpr int      kLog2Pix    = 20;           // 1024*1024 pixels/image
static constexpr unsigned kValidIds   = 0x01FFFFFEu;  // ids 1..24

__device__ __forceinline__ uint64_t mix64(uint64_t h) {
    h ^= h >> 30; h *= 0xbf58476d1ce4e5b9ULL;
    h ^= h >> 27; h *= 0x94d049bb133111ebULL;
    h ^= h >> 31;
    return h;
}

// grid = (256 blocks/batch, batches-in-group), block = 256 threads.
// Each block covers 4096 consecutive pixels of one image via float4/int4 loads.
__global__ __launch_bounds__(256)
void rp_insert(const float* __restrict__ ypr,
               const int*   __restrict__ wm,
               unsigned long long* __restrict__ table,
               uint64_t slot_mask,
               unsigned* __restrict__ distinct,
               unsigned* __restrict__ present,
               int b0)
{
    const int    b       = b0 + (int)blockIdx.y;
    const size_t vecBase = ((size_t)b << (kLog2Pix - 2)) + (size_t)blockIdx.x * 1024;

    unsigned localNew  = 0;
    unsigned localMask = 0;

    const float4* v4 = (const float4*)ypr;
    const int4*   m4 = (const int4*)wm;

    #pragma unroll
    for (int it = 0; it < 4; ++it) {
        const size_t vi = vecBase + (size_t)it * 256 + threadIdx.x;
        const float4 v = v4[vi];
        const int4   m = m4[vi];
        const float vals[4] = {v.x, v.y, v.z, v.w};
        const int   ids[4]  = {m.x, m.y, m.z, m.w};
        #pragma unroll
        for (int c = 0; c < 4; ++c) {
            const int id = ids[c];
            if (id <= 0) continue;              // id==0 excluded from the loss
            localMask |= (1u << id);
            const float fv = vals[c];
            unsigned bits = __float_as_uint(fv);
            if (fv == 0.0f) bits = 0u;          // -0.0 == 0.0 under float !=
            const uint64_t key =
                ((uint64_t)(unsigned)b << 37) |
                ((uint64_t)(unsigned)id << 32) |
                (uint64_t)bits;
            const unsigned long long stored = (unsigned long long)(key | (1ULL << 63));
            uint64_t pos = mix64(key) & slot_mask;
            for (int t = 0; t < 8192; ++t) {    // probe cap (safety; ~1.3 avg)
                const unsigned long long old = atomicCAS(&table[pos], 0ULL, stored);
                if (old == 0ULL)   { ++localNew; break; }
                if (old == stored) break;       // duplicate value in region
                pos = (pos + 1) & slot_mask;
            }
        }
    }

    // wave-64 butterfly reduce: sum of new inserts, OR of id-presence mask
    #pragma unroll
    for (int off = 32; off > 0; off >>= 1) {
        localNew  += __shfl_xor(localNew,  off);
        localMask |= __shfl_xor(localMask, off);
    }
    if ((threadIdx.x & 63u) == 0u) {
        if (localNew)  atomicAdd(&distinct[b], localNew);
        if (localMask) atomicOr(&present[b], localMask);
    }
}

// Exact float32 replay of the reference's sequential scan fold.
__global__ void rp_finalize(const unsigned* __restrict__ distinct,
                            const unsigned* __restrict__ present,
                            float* __restrict__ out)
{
    if (threadIdx.x == 0 && blockIdx.x == 0) {
        float loss = 0.0f;
        for (int b = 0; b < kBatches; ++b) {
            const int   nb = __popc(present[b] & kValidIds);
            const float Lb = (float)((int)distinct[b] - nb);
            loss = loss + Lb;
            if (nb > 0) loss = loss / (float)nb;   // IEEE RN division (no fast-math)
        }
        out[0] = loss;
    }
}

extern "C" void kernel_launch(void* const* d_in, const int* in_sizes, int n_in,
                              void* d_out, int out_size, void* d_ws, size_t ws_size,
                              hipStream_t stream)
{
    // setup_inputs order: tgt_img, y_tgt_pr, mask, weak_mask
    const float* ypr = (const float*)d_in[1];
    const int*   wm  = (const int*)d_in[3];
    float*       out = (float*)d_out;

    char* ws = (char*)d_ws;
    unsigned* distinct = (unsigned*)ws;               // 16 * u32
    unsigned* present  = (unsigned*)(ws + 64);        // 16 * u32
    unsigned long long* table = (unsigned long long*)(ws + 256);

    const size_t avail = (ws_size > 256) ? (ws_size - 256) : 0;
    uint64_t slots = 1;
    while ((slots * 2ULL) * 8ULL <= avail && slots < (1ULL << 24)) slots <<= 1;

    // batches per pass so worst-case load factor stays <= ~60%
    int g = (int)((slots * 3ULL / 5ULL) >> kLog2Pix);
    if (g < 1)  g = 1;
    if (g > 16) g = 16;

    // clear counters + table once; table again between passes (if any)
    hipMemsetAsync(ws, 0, 256 + (size_t)slots * 8ULL, stream);

    for (int b0 = 0; b0 < kBatches; b0 += g) {
        if (b0 > 0) hipMemsetAsync(ws + 256, 0, (size_t)slots * 8ULL, stream);
        const int gc = (kBatches - b0 < g) ? (kBatches - b0) : g;
        dim3 grid(256, gc);   // 256 blocks * 4096 px = 2^20 px per image
        rp_insert<<<grid, 256, 0, stream>>>(ypr, wm, table, slots - 1,
                                            distinct, present, b0);
    }

    rp_finalize<<<1, 64, 0, stream>>>(distinct, present, out);
}

// Round 7
// 749.584 us; speedup vs baseline: 1.8696x; 1.8696x over previous
//
#include <hip/hip_runtime.h>
#include <stdint.h>

// Exact distinct-(b,id,value) counting without device-scope atomics:
//   K1: stream input, bucket-partition 41-bit keys via an invertible
//       multiplicative permutation (bucket = top 10 permuted bits, store the
//       31-bit residual as u32), LDS-staged coalesced flushes.
//   K2: one block per bucket, exact dedup in a 32768-slot LDS hash table
//       (31-bit residual + valid bit fits u32), decode b/id via inverse
//       permutation for per-batch counts + presence masks.
//   K3: exact float32 replay of the reference scan fold.

typedef unsigned int uint;

static constexpr int      kBatches  = 16;
static constexpr unsigned kValidIds = 0x01FFFFFEu;  // ids 1..24
static constexpr int      NBKT      = 1024;
static constexpr int      SDEPTH    = 12;
static constexpr uint64_t MASK41    = (1ULL << 41) - 1;
static constexpr uint64_t MULT41    = 0x9E3779B97F4A7C15ULL & MASK41;  // odd

constexpr uint64_t inv41_of(uint64_t a) {
    uint64_t x = a;
    for (int i = 0; i < 6; ++i) x *= (2ULL - a * x);   // Newton, mod 2^64
    return x & MASK41;                                  // valid mod 2^41
}
static constexpr uint64_t INV41 = inv41_of(MULT41);
static_assert(((MULT41 * INV41) & MASK41) == 1, "inverse");

// ---------------- K1: partition ----------------
__global__ __launch_bounds__(256)
void k_partition(const float4* __restrict__ v4, const int4* __restrict__ m4,
                 uint* __restrict__ buckets, uint* __restrict__ gcnt8,
                 uint* __restrict__ lost, uint cap, uint cap8)
{
    __shared__ uint scnt[NBKT];
    __shared__ uint stage[NBKT][SDEPTH];

    const uint tid = threadIdx.x;
    for (uint i = tid; i < NBKT; i += 256) scnt[i] = 0;
    __syncthreads();

    const uint total = 16u << 18;                 // 4,194,304 float4s
    const uint stride = gridDim.x * 256;

    for (uint base = blockIdx.x * 256; base < total; base += stride) {
        const uint idx = base + tid;
        if (idx < total) {
            const float4 v = v4[idx];
            const int4   m = m4[idx];
            const uint   b = idx >> 18;           // image index
            const float vals[4] = {v.x, v.y, v.z, v.w};
            const int   ids[4]  = {m.x, m.y, m.z, m.w};
            #pragma unroll
            for (int c = 0; c < 4; ++c) {
                const int id = ids[c];
                if (id <= 0) continue;
                uint bits = __float_as_uint(vals[c]);
                if (vals[c] == 0.0f) bits = 0u;   // -0.0 == 0.0
                const uint64_t key =
                    ((uint64_t)b << 37) | ((uint64_t)(uint)id << 32) | (uint64_t)bits;
                const uint64_t p   = key * MULT41;        // low 41 bits used
                const uint     bkt = (uint)(p >> 31) & (NBKT - 1);
                const uint     res = (uint)p & 0x7FFFFFFFu;
                const uint pos = atomicAdd(&scnt[bkt], 1);
                if (pos < SDEPTH) {
                    stage[bkt][pos] = res;
                } else {                           // rare in-iteration overflow
                    const uint g = atomicAdd(&gcnt8[bkt], 1);
                    if (g < cap8) {
                        uint* dst = buckets + (size_t)bkt * cap + (size_t)g * 8;
                        ((uint4*)dst)[0] = make_uint4(res, 0xFFFFFFFFu, 0xFFFFFFFFu, 0xFFFFFFFFu);
                        ((uint4*)dst)[1] = make_uint4(0xFFFFFFFFu, 0xFFFFFFFFu, 0xFFFFFFFFu, 0xFFFFFFFFu);
                    } else atomicAdd(lost, 1);
                }
            }
        }
        __syncthreads();
        // flush full groups of 8 (32 B coalesced), keep leftovers staged
        for (uint bk = tid; bk < NBKT; bk += 256) {
            const uint c = scnt[bk];
            if (c >= 8) {
                const uint cc = (c < (uint)SDEPTH) ? c : (uint)SDEPTH;
                const uint g  = atomicAdd(&gcnt8[bk], 1);
                if (g < cap8) {
                    uint* dst = buckets + (size_t)bk * cap + (size_t)g * 8;
                    ((uint4*)dst)[0] = *(const uint4*)&stage[bk][0];
                    ((uint4*)dst)[1] = *(const uint4*)&stage[bk][4];
                } else atomicAdd(lost, 8);
                for (uint j = 8; j < cc; ++j) stage[bk][j - 8] = stage[bk][j];
                scnt[bk] = cc - 8;
            }
        }
        __syncthreads();
    }

    // final flush: pad partial groups with 0xFFFFFFFF dummies
    for (uint bk = tid; bk < NBKT; bk += 256) {
        const uint c = scnt[bk];                  // < 8 here
        if (c > 0) {
            const uint g = atomicAdd(&gcnt8[bk], 1);
            if (g < cap8) {
                uint s[8];
                #pragma unroll
                for (uint j = 0; j < 8; ++j)
                    s[j] = (j < c) ? stage[bk][j] : 0xFFFFFFFFu;
                uint* dst = buckets + (size_t)bk * cap + (size_t)g * 8;
                ((uint4*)dst)[0] = make_uint4(s[0], s[1], s[2], s[3]);
                ((uint4*)dst)[1] = make_uint4(s[4], s[5], s[6], s[7]);
            } else atomicAdd(lost, c);
        }
    }
}

// ---------------- K2: per-bucket exact dedup in LDS ----------------
__global__ __launch_bounds__(256)
void k_dedup(const uint* __restrict__ buckets, const uint* __restrict__ gcnt8,
             uint cap, uint cap8,
             uint* __restrict__ distinct, uint* __restrict__ present)
{
    __shared__ uint tab[32768];
    __shared__ uint cnt_b[16 * 64];
    __shared__ uint presm[16];

    const uint tid = threadIdx.x;
    #pragma unroll
    for (uint k = 0; k < 32; ++k)
        ((uint4*)tab)[tid + k * 256] = make_uint4(0, 0, 0, 0);
    for (uint i = tid; i < 16 * 64; i += 256) cnt_b[i] = 0;
    if (tid < 16) presm[tid] = 0;
    __syncthreads();

    const uint bkt  = blockIdx.x;
    uint ng = gcnt8[bkt]; if (ng > cap8) ng = cap8;
    const uint n = ng * 8;
    const uint* base = buckets + (size_t)bkt * cap;
    const uint lane = tid & 63u;

    for (uint i = tid; i < n; i += 256) {
        const uint res = base[i];
        if (res == 0xFFFFFFFFu) continue;         // dummy pad
        const uint val = res | 0x80000000u;       // valid-flag
        uint h = (res * 0x9E3779B1u) >> 17;       // 15-bit slot
        for (int t = 0; t < 32768; ++t) {
            const uint old = atomicCAS(&tab[h], 0u, val);
            if (old == 0u) {                      // new distinct key
                const uint64_t p   = ((uint64_t)bkt << 31) | (uint64_t)res;
                const uint64_t key = (p * INV41) & MASK41;
                const uint b  = (uint)(key >> 37);
                const uint id = (uint)(key >> 32) & 31u;
                atomicAdd(&cnt_b[b * 64 + lane], 1);
                if (!(presm[b] & (1u << id))) atomicOr(&presm[b], 1u << id);
                break;
            }
            if (old == val) break;                // duplicate value
            h = (h + 1) & 32767u;
        }
    }
    __syncthreads();

    if (tid < 16) {
        uint s = 0;
        for (uint j = 0; j < 64; ++j) s += cnt_b[tid * 64 + j];
        if (s) atomicAdd(&distinct[tid], s);
        const uint pm = presm[tid];
        if (pm) atomicOr(&present[tid], pm);
    }
}

// ---------------- K3: exact scan-fold replay ----------------
__global__ void rp_finalize(const uint* __restrict__ distinct,
                            const uint* __restrict__ present,
                            float* __restrict__ out)
{
    if (threadIdx.x == 0 && blockIdx.x == 0) {
        float loss = 0.0f;
        for (int b = 0; b < kBatches; ++b) {
            const int   nb = __popc(present[b] & kValidIds);
            const float Lb = (float)((int)distinct[b] - nb);
            loss = loss + Lb;
            if (nb > 0) loss = loss / (float)nb;  // IEEE RN division
        }
        out[0] = loss;
    }
}

extern "C" void kernel_launch(void* const* d_in, const int* in_sizes, int n_in,
                              void* d_out, int out_size, void* d_ws, size_t ws_size,
                              hipStream_t stream)
{
    // setup_inputs order: tgt_img, y_tgt_pr, mask, weak_mask
    const float4* ypr = (const float4*)d_in[1];
    const int4*   wm  = (const int4*)d_in[3];
    float*        out = (float*)d_out;

    char* ws = (char*)d_ws;
    uint* distinct = (uint*)ws;               // [0,64)
    uint* present  = (uint*)(ws + 64);        // [64,128)
    uint* lost     = (uint*)(ws + 128);       // [128,132)
    uint* gcnt8    = (uint*)(ws + 4096);      // [4096,8192)
    uint* buckets  = (uint*)(ws + 16384);

    const size_t avail = (ws_size > 16384) ? (ws_size - 16384) : 0;
    size_t caps = avail / ((size_t)NBKT * 4);
    if (caps > 32768) caps = 32768;
    const uint cap  = (uint)(caps & ~(size_t)7);
    const uint cap8 = cap / 8;

    hipMemsetAsync(ws, 0, 8192, stream);      // counters + gcnt8 only

    k_partition<<<768, 256, 0, stream>>>(ypr, wm, buckets, gcnt8, lost, cap, cap8);
    k_dedup<<<NBKT, 256, 0, stream>>>(buckets, gcnt8, cap, cap8, distinct, present);
    rp_finalize<<<1, 64, 0, stream>>>(distinct, present, out);
}

// Round 8
// 640.815 us; speedup vs baseline: 2.1869x; 1.1697x over previous
//
#include <hip/hip_runtime.h>
#include <stdint.h>

// Exact distinct-(b,id,value) counting without device-scope hash atomics:
//   K1: stream input, bucket-partition 41-bit keys via an invertible
//       multiplicative permutation (bucket = top 10 permuted bits, store the
//       31-bit residual as u32), LDS-staged coalesced flushes.
//       gcnt8 group counters padded to 1/cache-line (false-sharing fix).
//   K2: grid 2048 = (bucket, half by res bit 30); exact dedup in a
//       16384-slot LDS hash table (64 KB -> 2 blocks/CU for latency hiding).
//   K3: exact float32 replay of the reference scan fold.

typedef unsigned int uint;

static constexpr int      kBatches  = 16;
static constexpr unsigned kValidIds = 0x01FFFFFEu;  // ids 1..24
static constexpr int      NBKT      = 1024;
static constexpr int      SDEPTH    = 12;
static constexpr int      CPAD      = 16;           // gcnt8 stride (64 B line)
static constexpr uint64_t MASK41    = (1ULL << 41) - 1;
static constexpr uint64_t MULT41    = 0x9E3779B97F4A7C15ULL & MASK41;  // odd

constexpr uint64_t inv41_of(uint64_t a) {
    uint64_t x = a;
    for (int i = 0; i < 6; ++i) x *= (2ULL - a * x);   // Newton, mod 2^64
    return x & MASK41;                                  // valid mod 2^41
}
static constexpr uint64_t INV41 = inv41_of(MULT41);
static_assert(((MULT41 * INV41) & MASK41) == 1, "inverse");

// ---------------- K1: partition ----------------
__global__ __launch_bounds__(256)
void k_partition(const float4* __restrict__ v4, const int4* __restrict__ m4,
                 uint* __restrict__ buckets, uint* __restrict__ gcnt8,
                 uint* __restrict__ lost, uint cap, uint cap8)
{
    __shared__ uint scnt[NBKT];
    __shared__ uint stage[NBKT][SDEPTH];

    const uint tid = threadIdx.x;
    for (uint i = tid; i < NBKT; i += 256) scnt[i] = 0;
    __syncthreads();

    const uint total = 16u << 18;                 // 4,194,304 float4s
    const uint stride = gridDim.x * 256;

    for (uint base = blockIdx.x * 256; base < total; base += stride) {
        const uint idx = base + tid;
        if (idx < total) {
            const float4 v = v4[idx];
            const int4   m = m4[idx];
            const uint   b = idx >> 18;           // image index
            const float vals[4] = {v.x, v.y, v.z, v.w};
            const int   ids[4]  = {m.x, m.y, m.z, m.w};
            #pragma unroll
            for (int c = 0; c < 4; ++c) {
                const int id = ids[c];
                if (id <= 0) continue;
                uint bits = __float_as_uint(vals[c]);
                if (vals[c] == 0.0f) bits = 0u;   // -0.0 == 0.0
                const uint64_t key =
                    ((uint64_t)b << 37) | ((uint64_t)(uint)id << 32) | (uint64_t)bits;
                const uint64_t p   = key * MULT41;        // low 41 bits used
                const uint     bkt = (uint)(p >> 31) & (NBKT - 1);
                const uint     res = (uint)p & 0x7FFFFFFFu;
                const uint pos = atomicAdd(&scnt[bkt], 1);
                if (pos < SDEPTH) {
                    stage[bkt][pos] = res;
                } else {                           // rare in-iteration overflow
                    const uint g = atomicAdd(&gcnt8[bkt * CPAD], 1);
                    if (g < cap8) {
                        uint* dst = buckets + (size_t)bkt * cap + (size_t)g * 8;
                        ((uint4*)dst)[0] = make_uint4(res, 0xFFFFFFFFu, 0xFFFFFFFFu, 0xFFFFFFFFu);
                        ((uint4*)dst)[1] = make_uint4(0xFFFFFFFFu, 0xFFFFFFFFu, 0xFFFFFFFFu, 0xFFFFFFFFu);
                    } else atomicAdd(lost, 1);
                }
            }
        }
        __syncthreads();
        // flush full groups of 8 (32 B coalesced), keep leftovers staged
        for (uint bk = tid; bk < NBKT; bk += 256) {
            const uint c = scnt[bk];
            if (c >= 8) {
                const uint cc = (c < (uint)SDEPTH) ? c : (uint)SDEPTH;
                const uint g  = atomicAdd(&gcnt8[bk * CPAD], 1);
                if (g < cap8) {
                    uint* dst = buckets + (size_t)bk * cap + (size_t)g * 8;
                    ((uint4*)dst)[0] = *(const uint4*)&stage[bk][0];
                    ((uint4*)dst)[1] = *(const uint4*)&stage[bk][4];
                } else atomicAdd(lost, 8);
                for (uint j = 8; j < cc; ++j) stage[bk][j - 8] = stage[bk][j];
                scnt[bk] = cc - 8;
            }
        }
        __syncthreads();
    }

    // final flush: pad partial groups with 0xFFFFFFFF dummies
    for (uint bk = tid; bk < NBKT; bk += 256) {
        const uint c = scnt[bk];                  // < 8 here
        if (c > 0) {
            const uint g = atomicAdd(&gcnt8[bk * CPAD], 1);
            if (g < cap8) {
                uint s[8];
                #pragma unroll
                for (uint j = 0; j < 8; ++j)
                    s[j] = (j < c) ? stage[bk][j] : 0xFFFFFFFFu;
                uint* dst = buckets + (size_t)bk * cap + (size_t)g * 8;
                ((uint4*)dst)[0] = make_uint4(s[0], s[1], s[2], s[3]);
                ((uint4*)dst)[1] = make_uint4(s[4], s[5], s[6], s[7]);
            } else atomicAdd(lost, c);
        }
    }
}

// ---------------- K2: per-(bucket,half) exact dedup in LDS ----------------
// grid = 2048: bkt = blockIdx.x >> 1, half = blockIdx.x & 1 (res bit 30).
// 16384-slot table = 64 KB LDS -> 2 blocks/CU (vs 1 before) for latency hiding.
__global__ __launch_bounds__(256)
void k_dedup(const uint* __restrict__ buckets, const uint* __restrict__ gcnt8,
             uint cap, uint cap8,
             uint* __restrict__ distinct, uint* __restrict__ present)
{
    __shared__ uint tab[16384];
    __shared__ uint cnt_b[16 * 64];
    __shared__ uint presm[16];

    const uint tid = threadIdx.x;
    #pragma unroll
    for (uint k = 0; k < 16; ++k)
        ((uint4*)tab)[tid + k * 256] = make_uint4(0, 0, 0, 0);
    for (uint i = tid; i < 16 * 64; i += 256) cnt_b[i] = 0;
    if (tid < 16) presm[tid] = 0;
    __syncthreads();

    const uint bkt  = blockIdx.x >> 1;
    const uint half = blockIdx.x & 1u;
    uint ng = gcnt8[bkt * CPAD]; if (ng > cap8) ng = cap8;
    const uint n = ng * 8;
    const uint* base = buckets + (size_t)bkt * cap;
    const uint lane = tid & 63u;

    for (uint i = tid; i < n; i += 256) {
        const uint res = base[i];
        if (res == 0xFFFFFFFFu) continue;         // dummy pad (bit31 set)
        if (((res >> 30) & 1u) != half) continue; // other half's key
        const uint val = res | 0x80000000u;       // valid-flag
        uint h = (res * 0x9E3779B1u) >> 18;       // 14-bit slot
        for (int t = 0; t < 16384; ++t) {
            const uint old = atomicCAS(&tab[h], 0u, val);
            if (old == 0u) {                      // new distinct key
                const uint64_t p   = ((uint64_t)bkt << 31) | (uint64_t)res;
                const uint64_t key = (p * INV41) & MASK41;
                const uint b  = (uint)(key >> 37);
                const uint id = (uint)(key >> 32) & 31u;
                atomicAdd(&cnt_b[b * 64 + lane], 1);
                if (!(presm[b] & (1u << id))) atomicOr(&presm[b], 1u << id);
                break;
            }
            if (old == val) break;                // duplicate value
            h = (h + 1) & 16383u;
        }
    }
    __syncthreads();

    if (tid < 16) {
        uint s = 0;
        for (uint j = 0; j < 64; ++j) s += cnt_b[tid * 64 + j];
        if (s) atomicAdd(&distinct[tid], s);
        const uint pm = presm[tid];
        if (pm) atomicOr(&present[tid], pm);
    }
}

// ---------------- K3: exact scan-fold replay ----------------
__global__ void rp_finalize(const uint* __restrict__ distinct,
                            const uint* __restrict__ present,
                            float* __restrict__ out)
{
    if (threadIdx.x == 0 && blockIdx.x == 0) {
        float loss = 0.0f;
        for (int b = 0; b < kBatches; ++b) {
            const int   nb = __popc(present[b] & kValidIds);
            const float Lb = (float)((int)distinct[b] - nb);
            loss = loss + Lb;
            if (nb > 0) loss = loss / (float)nb;  // IEEE RN division
        }
        out[0] = loss;
    }
}

extern "C" void kernel_launch(void* const* d_in, const int* in_sizes, int n_in,
                              void* d_out, int out_size, void* d_ws, size_t ws_size,
                              hipStream_t stream)
{
    // setup_inputs order: tgt_img, y_tgt_pr, mask, weak_mask
    const float4* ypr = (const float4*)d_in[1];
    const int4*   wm  = (const int4*)d_in[3];
    float*        out = (float*)d_out;

    char* ws = (char*)d_ws;
    uint* distinct = (uint*)ws;               // [0,64)
    uint* present  = (uint*)(ws + 64);        // [64,128)
    uint* lost     = (uint*)(ws + 128);       // [128,132)
    uint* gcnt8    = (uint*)(ws + 4096);      // [4096, 4096+64KB): padded, 1/line
    uint* buckets  = (uint*)(ws + 131072);

    const size_t avail = (ws_size > 131072) ? (ws_size - 131072) : 0;
    size_t caps = avail / ((size_t)NBKT * 4);
    if (caps > 32768) caps = 32768;
    const uint cap  = (uint)(caps & ~(size_t)7);
    const uint cap8 = cap / 8;

    hipMemsetAsync(ws, 0, 131072, stream);    // counters + padded gcnt8

    k_partition<<<768, 256, 0, stream>>>(ypr, wm, buckets, gcnt8, lost, cap, cap8);
    k_dedup<<<2048, 256, 0, stream>>>(buckets, gcnt8, cap, cap8, distinct, present);
    rp_finalize<<<1, 64, 0, stream>>>(distinct, present, out);
}